// Round 15
// baseline (314.977 us; speedup 1.0000x reference)
//
#include <hip/hip_runtime.h>
#include <hip/hip_bf16.h>

typedef unsigned short u16;
typedef __attribute__((ext_vector_type(8))) short bf8v;   // 8 x bf16 (4 VGPRs)
typedef __attribute__((ext_vector_type(4))) float f4v;    // 4 x f32 acc

#define N_NODES 50000
#define N_EDGES 800000
#define ET (N_EDGES + N_NODES)
#define D1 128
#define D2 64
#define NEG 0.2f
#define EPSF 1e-16f
#define LOG2E 1.44269504f
#define NTILES_PAD 3128
#define NP (NTILES_PAD * 16) // 50048 rows

// ---- ws layout (float offsets) ----
#define O_XL1    0           // 6,400,000 f32
#define O_XR1    6400000     // 6,400,000 f32
#define O_AH     12800000    // x A-planes (3 x 3,203,072); first 6.4M reused as f32 h after gemm1
#define O_AM     16003072
#define O_AL     19206144
#define O_B1H    22409216    // 16384 f32 slots each
#define O_B1M    22425600
#define O_B1L    22441984
#define O_B2H    22458368    // 8192 f32 slots each
#define O_B2M    22466560
#define O_B2L    22474752
#define O_WF     22482944    // 1,024 f32
#define O_SRC    22483968    // 850,000 u16
#define O_DST    22908968    // 850,000 u16
#define O_DEG    23333968    // 50,000 int
#define O_ROWPTR 23383968    // 50,001 int
#define O_RANK   23433969    // 850,000 u16
#define O_CSR    23858969    // 850,000 u16
#define O_FLAGS  24283969    // 2 int
#define O_PART   24283971    // 196 int
#define O_HIST   24284167    // 256 int
#define O_BCUR   24284423    // 256 int
#define O_PERM   24284679    // 50,000 int

// ---- Wf internal offsets ----
#define W_BL1   0
#define W_BR1   128
#define W_ATT1  256
#define W_BIAS1 384
#define W_BL2   512
#define W_BR2   576
#define W_ATT2  640
#define W_BIAS2 704

#define NB_SCAN  196         // ceil(50000/256)
#define NB_CVT   3321        // (ET+255)/256
#define NB_PACKX 3128        // NP*128/8/256 (8 u16/thread/plane)
#define NB_PREP  (NB_CVT + NB_PACKX + 128 + 64 + 1)
#define NB_G1    3128        // gemm1 blocks (782 tile-groups x 4 col-chunks)
#define NB_SG    (NB_G1 + NB_CVT)

__device__ __forceinline__ float load_f32(const void* src, int i, int isbf16) {
    if (isbf16) {
        u16 u = ((const u16*)src)[i];
        return __uint_as_float((unsigned)u << 16);
    }
    return ((const float*)src)[i];
}
__device__ __forceinline__ u16 f2b(float v) {
    __hip_bfloat16 h = __float2bfloat16(v);
    return *(u16*)&h;
}
__device__ __forceinline__ float b2f(u16 u) { return __uint_as_float((unsigned)u << 16); }

// 3-way split: v ~ hi + mid + lo, error ~2^-24 |v|
__device__ __forceinline__ void split3(float v, u16& hi, u16& mid, u16& lo) {
    hi = f2b(v);
    float r1 = v - b2f(hi);
    mid = f2b(r1);
    float r2 = r1 - b2f(mid);
    lo = f2b(r2);
}

// ---- dtype detection (1 block) ----
__global__ __launch_bounds__(64) void detect_k(const u16* x16, const int* ei32, int* flags) {
    int lane = threadIdx.x;
    int hits = 0;
    for (int j = lane; j < 32768; j += 64) {
        u16 u = x16[2 * j];
        if (((u >> 7) & 0xFF) == 0xFF) hits++;
    }
#pragma unroll
    for (int off = 32; off > 0; off >>= 1) hits += __shfl_xor(hits, off);
    int nz = 0;
    if (lane < 32) nz = ei32[2 * lane + 1];
#pragma unroll
    for (int off = 32; off > 0; off >>= 1) nz |= __shfl_xor(nz, off);
    if (lane == 0) { flags[0] = hits ? 0 : 1; flags[1] = nz ? 0 : 1; }
}

// ---- prep: cvt(+rank) || pack_x || pack_w1 || pack_w2 || params ----
__global__ void prep_k(const int* __restrict__ ei,
                       u16* __restrict__ srcA, u16* __restrict__ dstA,
                       u16* __restrict__ rank, int* __restrict__ deg,
                       const void* x, u16* AH, u16* AM, u16* AL,
                       const void* Wl1, const void* Wr1, u16* B1H, u16* B1M, u16* B1L,
                       const void* Wl2, const void* Wr2, u16* B2H, u16* B2M, u16* B2L,
                       const void* bl1, const void* br1, const void* att1, const void* bias1,
                       const void* bl2, const void* br2, const void* att2, const void* bias2,
                       float* Wf, const int* flags) {
    int b = blockIdx.x, t = threadIdx.x;
    int fb = flags[0];
    if (b < NB_CVT) {
        int e = b * 256 + t;
        if (e < ET) {
            int s, d;
            if (e < N_EDGES) {
                if (flags[1]) { s = ei[2 * e]; d = ei[2 * (N_EDGES + e)]; }
                else          { s = ei[e];     d = ei[N_EDGES + e]; }
            } else {
                s = d = e - N_EDGES;
            }
            srcA[e] = (u16)s; dstA[e] = (u16)d;
            rank[e] = (u16)atomicAdd(&deg[d], 1);
        }
        return;
    }
    b -= NB_CVT;
    if (b < NB_PACKX) {
        int i = b * 256 + t;            // i < 800768 exactly
        int j = i * 8;                  // output u16 index
        int tile = j >> 11;
        int jj = j & 2047;
        int r = tile * 16 + ((jj >> 3) & 15);
        int k0 = (jj >> 7) * 8;
        uint4 H = {0, 0, 0, 0}, M = {0, 0, 0, 0}, L = {0, 0, 0, 0};
        u16* Hp = (u16*)&H; u16* Mp = (u16*)&M; u16* Lp = (u16*)&L;
        if (r < N_NODES) {
            if (fb) {
                H = *(const uint4*)((const u16*)x + r * D1 + k0);   // exact bf16: mid=lo=0
            } else {
                float4 xa = *(const float4*)((const float*)x + r * D1 + k0);
                float4 xb = *(const float4*)((const float*)x + r * D1 + k0 + 4);
                float vv[8] = {xa.x, xa.y, xa.z, xa.w, xb.x, xb.y, xb.z, xb.w};
#pragma unroll
                for (int e2 = 0; e2 < 8; e2++) split3(vv[e2], Hp[e2], Mp[e2], Lp[e2]);
            }
        }
        *(uint4*)(AH + j) = H;
        *(uint4*)(AM + j) = M;
        *(uint4*)(AL + j) = L;
        return;
    }
    b -= NB_PACKX;
    if (b < 128) {
        int i = b * 256 + t;           // i < 32768
        int k = i >> 8, n = i & 255;
        float v = (n < 128) ? load_f32(Wl1, k * 128 + n, fb)
                            : load_f32(Wr1, k * 128 + (n - 128), fb);
        u16 hi, mid, lo; split3(v, hi, mid, lo);
        int idx = ((k >> 3) * 256 + n) * 8 + (k & 7);
        B1H[idx] = hi; B1M[idx] = mid; B1L[idx] = lo;
        return;
    }
    b -= 128;
    if (b < 64) {
        int i = b * 256 + t;           // i < 16384
        int k = i >> 7, n = i & 127;
        float v = (n < 64) ? load_f32(Wl2, k * 64 + n, fb)
                           : load_f32(Wr2, k * 64 + (n - 64), fb);
        u16 hi, mid, lo; split3(v, hi, mid, lo);
        int idx = ((k >> 3) * 128 + n) * 8 + (k & 7);
        B2H[idx] = hi; B2M[idx] = mid; B2L[idx] = lo;
        return;
    }
    if (t < 128) {
        Wf[W_BL1 + t]   = load_f32(bl1, t, fb);
        Wf[W_BR1 + t]   = load_f32(br1, t, fb);
        Wf[W_ATT1 + t]  = load_f32(att1, t, fb);
        Wf[W_BIAS1 + t] = load_f32(bias1, t, fb);
        if (t < 64) {
            Wf[W_BL2 + t]   = load_f32(bl2, t, fb);
            Wf[W_BR2 + t]   = load_f32(br2, t, fb);
            Wf[W_ATT2 + t]  = load_f32(att2, t, fb);
            Wf[W_BIAS2 + t] = load_f32(bias2, t, fb);
        }
    }
}

// ---- sa: scanA block-sums (0..195) || LDS-privatized degree histogram (196..391) ----
__global__ __launch_bounds__(256) void sa_k(const int* __restrict__ deg, int* __restrict__ part,
                                            int* __restrict__ hist) {
    int b = blockIdx.x, t = threadIdx.x;
    if (b < NB_SCAN) {
        __shared__ int s[256];
        int i = b * 256 + t;
        s[t] = (i < N_NODES) ? deg[i] : 0;
        __syncthreads();
        for (int off = 128; off > 0; off >>= 1) {
            if (t < off) s[t] += s[t + off];
            __syncthreads();
        }
        if (t == 0) part[b] = s[0];
        return;
    }
    __shared__ int lh[256];
    lh[t] = 0;
    __syncthreads();
    int i = (b - NB_SCAN) * 256 + t;
    if (i < N_NODES) atomicAdd(&lh[min(deg[i], 255)], 1);   // LDS atomic: block-local
    __syncthreads();
    if (lh[t]) atomicAdd(&hist[t], lh[t]);                  // one global atomic per (block,bucket)
}

// ---- sb: block0 = scan part[196]; block1 = bucket offsets from hist ----
__global__ __launch_bounds__(256) void sb_k(int* __restrict__ part, const int* __restrict__ hist,
                                            int* __restrict__ bcur) {
    __shared__ int s[256];
    int t = threadIdx.x;
    if (blockIdx.x == 0) {
        s[t] = (t < NB_SCAN) ? part[t] : 0;
        __syncthreads();
        for (int off = 1; off < 256; off <<= 1) {
            int v = (t >= off) ? s[t - off] : 0;
            __syncthreads();
            s[t] += v;
            __syncthreads();
        }
        if (t < NB_SCAN) part[t] = (t == 0) ? 0 : s[t - 1];
        return;
    }
    int h = hist[t];
    s[t] = h;
    __syncthreads();
    for (int off = 1; off < 256; off <<= 1) {
        int v = (t >= off) ? s[t - off] : 0;
        __syncthreads();
        s[t] += v;
        __syncthreads();
    }
    bcur[t] = s[t] - h;   // exclusive
}

// ---- sc: rowptr (0..195) || block-aggregated perm scatter (196..391) ----
__global__ __launch_bounds__(256) void sc_k(const int* __restrict__ deg, const int* __restrict__ part,
                                            int* __restrict__ rowptr,
                                            int* __restrict__ bcur, int* __restrict__ perm) {
    int b = blockIdx.x, t = threadIdx.x;
    if (b < NB_SCAN) {
        __shared__ int s[256];
        int i = b * 256 + t;
        int v = (i < N_NODES) ? deg[i] : 0;
        s[t] = v;
        __syncthreads();
        for (int off = 1; off < 256; off <<= 1) {
            int u = (t >= off) ? s[t - off] : 0;
            __syncthreads();
            s[t] += u;
            __syncthreads();
        }
        int excl = part[b] + s[t] - v;
        if (i < N_NODES) rowptr[i] = excl;
        if (i == N_NODES - 1) rowptr[N_NODES] = excl + v;
        return;
    }
    __shared__ int lh[256];
    __shared__ int lbase[256];
    lh[t] = 0;
    __syncthreads();
    int i = (b - NB_SCAN) * 256 + t;
    int bk = -1, myrank = 0;
    if (i < N_NODES) {
        bk = min(deg[i], 255);
        myrank = atomicAdd(&lh[bk], 1);     // LDS atomic
    }
    __syncthreads();
    if (lh[t]) lbase[t] = atomicAdd(&bcur[t], lh[t]);   // 1 global atomic per bucket
    __syncthreads();
    if (bk >= 0) perm[lbase[bk] + myrank] = i;
}

// 6-term split-precision MFMA accumulate: acc += A*B with ~2^-24 relative error
#define MFMA6(acc, ah, am, al, bh, bm, bl)                                    \
    acc = __builtin_amdgcn_mfma_f32_16x16x32_bf16(ah, bl, acc, 0, 0, 0);      \
    acc = __builtin_amdgcn_mfma_f32_16x16x32_bf16(am, bm, acc, 0, 0, 0);      \
    acc = __builtin_amdgcn_mfma_f32_16x16x32_bf16(al, bh, acc, 0, 0, 0);      \
    acc = __builtin_amdgcn_mfma_f32_16x16x32_bf16(ah, bm, acc, 0, 0, 0);      \
    acc = __builtin_amdgcn_mfma_f32_16x16x32_bf16(am, bh, acc, 0, 0, 0);      \
    acc = __builtin_amdgcn_mfma_f32_16x16x32_bf16(ah, bh, acc, 0, 0, 0);

// ---- sg: gemm1 (blocks [0,NB_G1)) || atomic-free csr scatter ----
__global__ __launch_bounds__(256) void sg_k(const u16* __restrict__ AH, const u16* __restrict__ AM,
                                            const u16* __restrict__ AL,
                                            const u16* __restrict__ BH, const u16* __restrict__ BM,
                                            const u16* __restrict__ BL,
                                            const float* __restrict__ Wf,
                                            float* __restrict__ xl, float* __restrict__ xr,
                                            const u16* __restrict__ srcA, const u16* __restrict__ dstA,
                                            const u16* __restrict__ rank, const int* __restrict__ rowptr,
                                            u16* __restrict__ csr) {
    int b = blockIdx.x;
    if (b < NB_G1) {
        int w = threadIdx.x >> 6, l = threadIdx.x & 63;
        int tile = (b >> 2) * 4 + w;
        int cb = (b & 3) << 6;                 // col base (0,64,128,192)
        int lr = l & 15, lg = l >> 4;
        f4v acc[4];
#pragma unroll
        for (int nt = 0; nt < 4; nt++) acc[nt] = (f4v)(0.f);
        int aoff = tile * 2048 + lg * 128 + lr * 8;
#pragma unroll
        for (int ks = 0; ks < 4; ks++) {
            bf8v ah = *(const bf8v*)(AH + aoff + ks * 512);
            bf8v am = *(const bf8v*)(AM + aoff + ks * 512);
            bf8v al = *(const bf8v*)(AL + aoff + ks * 512);
            int boff = ((ks * 4 + lg) * 256 + cb + lr) * 8;
#pragma unroll
            for (int nt = 0; nt < 4; nt++) {
                bf8v bh = *(const bf8v*)(BH + boff + nt * 128);
                bf8v bm = *(const bf8v*)(BM + boff + nt * 128);
                bf8v bl = *(const bf8v*)(BL + boff + nt * 128);
                MFMA6(acc[nt], ah, am, al, bh, bm, bl)
            }
        }
        int r0 = tile * 16 + lg * 4;
        if (r0 >= N_NODES) return;
#pragma unroll
        for (int nt = 0; nt < 4; nt++) {
            int col = cb + nt * 16 + lr;
            float bias = (col < D1) ? Wf[W_BL1 + col] : Wf[W_BR1 + col - D1];
            float* dst = (col < D1) ? (xl + col) : (xr + col - D1);
#pragma unroll
            for (int j = 0; j < 4; j++) {
                int row = r0 + j;
                dst[(size_t)row * D1] = acc[nt][j] + bias;
            }
        }
        return;
    }
    int e = (b - NB_G1) * 256 + threadIdx.x;
    if (e < ET) {
        int d = dstA[e];
        csr[rowptr[d] + rank[e]] = srcA[e];    // unique slot, no atomic
    }
}

// MFMA GEMM 2: A read from f32 h rows, in-register split3. Grid (782, 2) x 256 thr.
union bfu { bf8v v; u16 s[8]; };
__global__ __launch_bounds__(256) void gemm2_mfma(const float* __restrict__ hA,
                                                  const u16* __restrict__ BH, const u16* __restrict__ BM,
                                                  const u16* __restrict__ BL,
                                                  const float* __restrict__ Wf,
                                                  float* __restrict__ xl2, float* __restrict__ xr2) {
    int w = threadIdx.x >> 6, l = threadIdx.x & 63;
    int tile = blockIdx.x * 4 + w;
    int cb = blockIdx.y << 6;                 // col base (0,64)
    int lr = l & 15, lg = l >> 4;
    int r = tile * 16 + lr;
    int rc = min(r, N_NODES - 1);             // pad rows read row 49999; stores guarded off
    f4v acc[4];
#pragma unroll
    for (int nt = 0; nt < 4; nt++) acc[nt] = (f4v)(0.f);
#pragma unroll
    for (int ks = 0; ks < 4; ks++) {
        const float* hp = hA + (size_t)rc * D1 + ks * 32 + lg * 8;
        float4 p0 = *(const float4*)hp;
        float4 p1 = *(const float4*)(hp + 4);
        float vv[8] = {p0.x, p0.y, p0.z, p0.w, p1.x, p1.y, p1.z, p1.w};
        bfu ah, am, al;
#pragma unroll
        for (int j = 0; j < 8; j++) split3(vv[j], ah.s[j], am.s[j], al.s[j]);
        int boff = ((ks * 4 + lg) * 128 + cb + lr) * 8;
#pragma unroll
        for (int nt = 0; nt < 4; nt++) {
            bf8v bh = *(const bf8v*)(BH + boff + nt * 128);
            bf8v bm = *(const bf8v*)(BM + boff + nt * 128);
            bf8v bl = *(const bf8v*)(BL + boff + nt * 128);
            MFMA6(acc[nt], ah.v, am.v, al.v, bh, bm, bl)
        }
    }
    int r0 = tile * 16 + lg * 4;
    if (r0 >= N_NODES) return;
#pragma unroll
    for (int nt = 0; nt < 4; nt++) {
        int col = cb + nt * 16 + lr;
        float bias = (col < D2) ? Wf[W_BL2 + col] : Wf[W_BR2 + col - D2];
        float* dst = (col < D2) ? (xl2 + col) : (xr2 + col - D2);
#pragma unroll
        for (int j = 0; j < 4; j++) {
            int row = r0 + j;
            dst[(size_t)row * D2] = acc[nt][j] + bias;
        }
    }
}

// layer-1 aggregation: degree-sorted nodes (perm), 32 lanes/node, no-max softmax (exp2,
// att pre-scaled by log2e, med3 clamp), 2-deep gather prefetch, + bias1 + ELU -> f32 h rows.
#define L1STEP(a)                                                              \
    {                                                                          \
        float m0 = a.x + xr4.x; m0 = fmaxf(m0, NEG * m0);                      \
        float m1 = a.y + xr4.y; m1 = fmaxf(m1, NEG * m1);                      \
        float m2 = a.z + xr4.z; m2 = fmaxf(m2, NEG * m2);                      \
        float m3 = a.w + xr4.w; m3 = fmaxf(m3, NEG * m3);                      \
        float p = m0 * at4.x + m1 * at4.y + m2 * at4.z + m3 * at4.w;           \
        p += __shfl_xor(p, 1);                                                 \
        p += __shfl_xor(p, 2);                                                 \
        p = __builtin_amdgcn_fmed3f(p, -86.f, 86.f);                           \
        float wgt = exp2f(p);                                                  \
        l += wgt;                                                              \
        acc.x = fmaf(wgt, a.x, acc.x);                                         \
        acc.y = fmaf(wgt, a.y, acc.y);                                         \
        acc.z = fmaf(wgt, a.z, acc.z);                                         \
        acc.w = fmaf(wgt, a.w, acc.w);                                         \
    }

__global__ __launch_bounds__(256) void l1_agg(const int* __restrict__ rowptr, const u16* __restrict__ csr,
                                              const int* __restrict__ perm,
                                              const float* __restrict__ xl, const float* __restrict__ xr,
                                              const float* __restrict__ Wf, float* __restrict__ hbuf) {
    int n = perm[(blockIdx.x * 256 + threadIdx.x) >> 5];
    int q = threadIdx.x & 31;                        // channels 4q..4q+3
    const float4* xl4 = (const float4*)xl;
    float4 xr4 = ((const float4*)(xr + (size_t)n * D1))[q];
    float4 at4 = ((const float4*)(Wf + W_ATT1))[q];
    at4.x *= LOG2E; at4.y *= LOG2E; at4.z *= LOG2E; at4.w *= LOG2E;
    int i0 = rowptr[n], i1 = rowptr[n + 1];
    float l = 0.f;
    float4 acc = {0.f, 0.f, 0.f, 0.f};
    float4 a0 = xl4[(size_t)csr[i0] * 32 + q];       // deg >= 1 (self-loop)
    if (i0 + 1 < i1) {
        float4 a1 = xl4[(size_t)csr[i0 + 1] * 32 + q];
        for (int i = i0 + 2; i < i1; i++) {
            float4 a2 = xl4[(size_t)csr[i] * 32 + q];  // 2-deep prefetch
            L1STEP(a0)
            a0 = a1; a1 = a2;
        }
        L1STEP(a0)
        a0 = a1;
    }
    L1STEP(a0)
    float rinv = 1.f / l;
    float4 bi4 = ((const float4*)(Wf + W_BIAS1))[q];
    float v0 = acc.x * rinv + bi4.x; v0 = v0 > 0.f ? v0 : expm1f(v0);
    float v1 = acc.y * rinv + bi4.y; v1 = v1 > 0.f ? v1 : expm1f(v1);
    float v2 = acc.z * rinv + bi4.z; v2 = v2 > 0.f ? v2 : expm1f(v2);
    float v3 = acc.w * rinv + bi4.w; v3 = v3 > 0.f ? v3 : expm1f(v3);
    float4 hv = {v0, v1, v2, v3};
    ((float4*)(hbuf + (size_t)n * D1))[q] = hv;      // contiguous 512B/node, perm-safe
}

// layer-2 aggregation: degree-sorted nodes (perm), 16 lanes/node, no-max softmax (exp2),
// 2-deep prefetch, + bias2 + log_softmax + argmax. Grid 3125 x 256.
#define L2STEP(a)                                                              \
    {                                                                          \
        float m0 = a.x + xr4.x; m0 = fmaxf(m0, NEG * m0);                      \
        float m1 = a.y + xr4.y; m1 = fmaxf(m1, NEG * m1);                      \
        float m2 = a.z + xr4.z; m2 = fmaxf(m2, NEG * m2);                      \
        float m3 = a.w + xr4.w; m3 = fmaxf(m3, NEG * m3);                      \
        float p = m0 * at4.x + m1 * at4.y + m2 * at4.z + m3 * at4.w;           \
        p += __shfl_xor(p, 1);                                                 \
        p += __shfl_xor(p, 2);                                                 \
        p += __shfl_xor(p, 4);                                                 \
        p += __shfl_xor(p, 8);                                                 \
        p = __builtin_amdgcn_fmed3f(p, -115.f, 115.f);                         \
        float wgt = exp2f(p);                                                  \
        l += wgt;                                                              \
        acc.x = fmaf(wgt, a.x, acc.x);                                         \
        acc.y = fmaf(wgt, a.y, acc.y);                                         \
        acc.z = fmaf(wgt, a.z, acc.z);                                         \
        acc.w = fmaf(wgt, a.w, acc.w);                                         \
    }

__global__ __launch_bounds__(256) void l2_agg(const int* __restrict__ rowptr, const u16* __restrict__ csr,
                                              const int* __restrict__ perm,
                                              const float* __restrict__ xl, const float* __restrict__ xr,
                                              const float* __restrict__ Wf, float* __restrict__ out) {
    int n = perm[(blockIdx.x * 256 + threadIdx.x) >> 4];
    int q = threadIdx.x & 15;                        // channels 4q..4q+3
    const float4* xl4 = (const float4*)xl;
    float4 xr4 = ((const float4*)(xr + (size_t)n * D2))[q];
    float4 at4 = ((const float4*)(Wf + W_ATT2))[q];
    at4.x *= LOG2E; at4.y *= LOG2E; at4.z *= LOG2E; at4.w *= LOG2E;
    int i0 = rowptr[n], i1 = rowptr[n + 1];
    float l = 0.f;
    float4 acc = {0.f, 0.f, 0.f, 0.f};
    float4 a0 = xl4[(size_t)csr[i0] * 16 + q];
    if (i0 + 1 < i1) {
        float4 a1 = xl4[(size_t)csr[i0 + 1] * 16 + q];
        for (int i = i0 + 2; i < i1; i++) {
            float4 a2 = xl4[(size_t)csr[i] * 16 + q];
            L2STEP(a0)
            a0 = a1; a1 = a2;
        }
        L2STEP(a0)
        a0 = a1;
    }
    L2STEP(a0)
    float rinv = 1.f / (l + EPSF);
    float4 bi4 = ((const float4*)(Wf + W_BIAS2))[q];
    float v0 = acc.x * rinv + bi4.x;
    float v1 = acc.y * rinv + bi4.y;
    float v2 = acc.z * rinv + bi4.z;
    float v3 = acc.w * rinv + bi4.w;
    float4 hv = {v0, v1, v2, v3};
    ((float4*)(out + (size_t)n * D2))[q] = hv;
    // log-softmax over 64 classes = 16 lanes x 4
    float mx = fmaxf(fmaxf(v0, v1), fmaxf(v2, v3));
#pragma unroll
    for (int off = 1; off < 16; off <<= 1) mx = fmaxf(mx, __shfl_xor(mx, off));
    float sum = expf(v0 - mx) + expf(v1 - mx) + expf(v2 - mx) + expf(v3 - mx);
#pragma unroll
    for (int off = 1; off < 16; off <<= 1) sum += __shfl_xor(sum, off);
    float lse = mx + logf(sum);
    float4 ls = {v0 - lse, v1 - lse, v2 - lse, v3 - lse};
    ((float4*)(out + (size_t)N_NODES * D2 + (size_t)n * D2))[q] = ls;
    // argmax, first occurrence on ties (channels 4q+j are lane-contiguous)
    float bv = v0; int bi = 4 * q;
    if (v1 > bv) { bv = v1; bi = 4 * q + 1; }
    if (v2 > bv) { bv = v2; bi = 4 * q + 2; }
    if (v3 > bv) { bv = v3; bi = 4 * q + 3; }
#pragma unroll
    for (int off = 1; off < 16; off <<= 1) {
        float ov = __shfl_xor(bv, off);
        int   oi = __shfl_xor(bi, off);
        if (ov > bv || (ov == bv && oi < bi)) { bv = ov; bi = oi; }
    }
    if (q == 0) out[(size_t)2 * N_NODES * D2 + n] = (float)bi;
}

extern "C" void kernel_launch(void* const* d_in, const int* in_sizes, int n_in,
                              void* d_out, int out_size, void* d_ws, size_t ws_size,
                              hipStream_t stream) {
    const void* x  = d_in[0];
    const int*  ei = (const int*)d_in[1];

    float* ws = (float*)d_ws;
    float* xl1    = ws + O_XL1;
    float* xr1    = ws + O_XR1;
    u16*   AH     = (u16*)(ws + O_AH);
    u16*   AM     = (u16*)(ws + O_AM);
    u16*   AL     = (u16*)(ws + O_AL);
    float* hbuf   = ws + O_AH;           // f32 h reuses A-plane region after gemm1
    u16*   B1H    = (u16*)(ws + O_B1H);
    u16*   B1M    = (u16*)(ws + O_B1M);
    u16*   B1L    = (u16*)(ws + O_B1L);
    u16*   B2H    = (u16*)(ws + O_B2H);
    u16*   B2M    = (u16*)(ws + O_B2M);
    u16*   B2L    = (u16*)(ws + O_B2L);
    float* Wf     = ws + O_WF;
    u16*   srcA   = (u16*)(ws + O_SRC);
    u16*   dstA   = (u16*)(ws + O_DST);
    int*   deg    = (int*)(ws + O_DEG);
    int*   rowptr = (int*)(ws + O_ROWPTR);
    u16*   rank   = (u16*)(ws + O_RANK);
    u16*   csr    = (u16*)(ws + O_CSR);
    int*   flags  = (int*)(ws + O_FLAGS);
    int*   part   = (int*)(ws + O_PART);
    int*   hist   = (int*)(ws + O_HIST);
    int*   bcur   = (int*)(ws + O_BCUR);
    int*   perm   = (int*)(ws + O_PERM);

    float* xl2 = xl1;
    float* xr2 = xl1 + 3200000;

    hipMemsetAsync(deg, 0, N_NODES * sizeof(int), stream);
    hipMemsetAsync(hist, 0, 256 * sizeof(int), stream);
    detect_k<<<1, 64, 0, stream>>>((const u16*)x, ei, flags);
    prep_k<<<NB_PREP, 256, 0, stream>>>(ei, srcA, dstA, rank, deg,
                                        x, AH, AM, AL,
                                        d_in[2], d_in[4], B1H, B1M, B1L,
                                        d_in[8], d_in[10], B2H, B2M, B2L,
                                        d_in[3], d_in[5], d_in[6], d_in[7],
                                        d_in[9], d_in[11], d_in[12], d_in[13],
                                        Wf, flags);
    sa_k<<<2 * NB_SCAN, 256, 0, stream>>>(deg, part, hist);
    sb_k<<<2, 256, 0, stream>>>(part, hist, bcur);
    sc_k<<<2 * NB_SCAN, 256, 0, stream>>>(deg, part, rowptr, bcur, perm);
    sg_k<<<NB_SG, 256, 0, stream>>>(AH, AM, AL, B1H, B1M, B1L, Wf, xl1, xr1,
                                    srcA, dstA, rank, rowptr, csr);

    l1_agg<<<6250, 256, 0, stream>>>(rowptr, csr, perm, xl1, xr1, Wf, hbuf);
    gemm2_mfma<<<dim3(NTILES_PAD / 4, 2), 256, 0, stream>>>(hbuf, B2H, B2M, B2L, Wf, xl2, xr2);
    l2_agg<<<3125, 256, 0, stream>>>(rowptr, csr, perm, xl2, xr2, Wf, (float*)d_out);
}

// Round 16
// 248.239 us; speedup vs baseline: 1.2688x; 1.2688x over previous
//
#include <hip/hip_runtime.h>
#include <hip/hip_bf16.h>

typedef unsigned short u16;
typedef __attribute__((ext_vector_type(8))) short bf8v;   // 8 x bf16 (4 VGPRs)
typedef __attribute__((ext_vector_type(4))) float f4v;    // 4 x f32 acc

#define N_NODES 50000
#define N_EDGES 800000
#define ET (N_EDGES + N_NODES)
#define D1 128
#define D2 64
#define NEG 0.2f
#define EPSF 1e-16f
#define LOG2E 1.44269504f
#define NTILES_PAD 3128
#define NP (NTILES_PAD * 16) // 50048 rows

// ---- ws layout (float offsets) ----
#define O_XL1    0           // 6,400,000 f32
#define O_XR1    6400000     // 6,400,000 f32
#define O_AH     12800000    // x A-planes (3 x 3,203,072); first 6.4M reused as f32 h after gemm1
#define O_AM     16003072
#define O_AL     19206144
#define O_B1H    22409216    // 16384 f32 slots each
#define O_B1M    22425600
#define O_B1L    22441984
#define O_B2H    22458368    // 8192 f32 slots each
#define O_B2M    22466560
#define O_B2L    22474752
#define O_WF     22482944    // 1,024 f32
#define O_SRC    22483968    // 850,000 u16
#define O_DST    22908968    // 850,000 u16
#define O_DEG    23333968    // 50,000 int
#define O_ROWPTR 23383968    // 50,001 int
#define O_RANK   23433969    // 850,000 u16
#define O_CSR    23858969    // 850,000 u16
#define O_FLAGS  24283969    // 2 int
#define O_PART   24283971    // 196 int
#define O_HIST   24284167    // 256 int
#define O_BCUR   24284423    // 256 int
#define O_PERM   24284679    // 50,000 int

// ---- Wf internal offsets ----
#define W_BL1   0
#define W_BR1   128
#define W_ATT1  256
#define W_BIAS1 384
#define W_BL2   512
#define W_BR2   576
#define W_ATT2  640
#define W_BIAS2 704

#define NB_SCAN  196         // ceil(50000/256)
#define NB_CVT   3321        // (ET+255)/256
#define NB_PACKX 3128        // NP*128/8/256 (8 u16/thread/plane)
#define NB_PREP  (NB_CVT + NB_PACKX + 128 + 64 + 1)
#define NB_G1    3128        // gemm1 blocks (782 tile-groups x 4 col-chunks)
#define NB_SG    (NB_G1 + NB_CVT)

__device__ __forceinline__ float load_f32(const void* src, int i, int isbf16) {
    if (isbf16) {
        u16 u = ((const u16*)src)[i];
        return __uint_as_float((unsigned)u << 16);
    }
    return ((const float*)src)[i];
}
__device__ __forceinline__ u16 f2b(float v) {
    __hip_bfloat16 h = __float2bfloat16(v);
    return *(u16*)&h;
}
__device__ __forceinline__ float b2f(u16 u) { return __uint_as_float((unsigned)u << 16); }

// 3-way split: v ~ hi + mid + lo, error ~2^-24 |v|
__device__ __forceinline__ void split3(float v, u16& hi, u16& mid, u16& lo) {
    hi = f2b(v);
    float r1 = v - b2f(hi);
    mid = f2b(r1);
    float r2 = r1 - b2f(mid);
    lo = f2b(r2);
}

// ---- dtype detection: 256 threads, 32 independent uint4 loads each (MLP-parallel).
// Even-indexed u16s are the LOW halves of each 32-bit word; bits 7-14 = f32 low-mantissa
// (random, hits 0xFF with p=2^-8) or bf16 exponent (never 0xFF for sane data).
__global__ __launch_bounds__(256) void detect_k(const uint4* __restrict__ x4,
                                                const int* __restrict__ ei32, int* flags) {
    __shared__ int sh_hits, sh_nz;
    int t = threadIdx.x;
    if (t == 0) { sh_hits = 0; sh_nz = 0; }
    __syncthreads();
    int hits = 0;
#pragma unroll 8
    for (int it = 0; it < 32; it++) {
        uint4 v = x4[it * 256 + t];              // coalesced, 32 loads in flight
        if (((v.x >> 7) & 0xFF) == 0xFF) hits++;
        if (((v.y >> 7) & 0xFF) == 0xFF) hits++;
        if (((v.z >> 7) & 0xFF) == 0xFF) hits++;
        if (((v.w >> 7) & 0xFF) == 0xFF) hits++;
    }
    int nz = (t < 32) ? ei32[2 * t + 1] : 0;     // odd words zero <=> int64 indices
#pragma unroll
    for (int off = 32; off > 0; off >>= 1) {
        hits += __shfl_xor(hits, off);
        nz   |= __shfl_xor(nz, off);
    }
    if ((t & 63) == 0) {
        if (hits) atomicAdd(&sh_hits, hits);
        if (nz)   atomicOr(&sh_nz, 1);
    }
    __syncthreads();
    if (t == 0) { flags[0] = sh_hits ? 0 : 1; flags[1] = sh_nz ? 0 : 1; }
}

// ---- prep: cvt(+rank) || pack_x || pack_w1 || pack_w2 || params ----
__global__ void prep_k(const int* __restrict__ ei,
                       u16* __restrict__ srcA, u16* __restrict__ dstA,
                       u16* __restrict__ rank, int* __restrict__ deg,
                       const void* x, u16* AH, u16* AM, u16* AL,
                       const void* Wl1, const void* Wr1, u16* B1H, u16* B1M, u16* B1L,
                       const void* Wl2, const void* Wr2, u16* B2H, u16* B2M, u16* B2L,
                       const void* bl1, const void* br1, const void* att1, const void* bias1,
                       const void* bl2, const void* br2, const void* att2, const void* bias2,
                       float* Wf, const int* flags) {
    int b = blockIdx.x, t = threadIdx.x;
    int fb = flags[0];
    if (b < NB_CVT) {
        int e = b * 256 + t;
        if (e < ET) {
            int s, d;
            if (e < N_EDGES) {
                if (flags[1]) { s = ei[2 * e]; d = ei[2 * (N_EDGES + e)]; }
                else          { s = ei[e];     d = ei[N_EDGES + e]; }
            } else {
                s = d = e - N_EDGES;
            }
            srcA[e] = (u16)s; dstA[e] = (u16)d;
            rank[e] = (u16)atomicAdd(&deg[d], 1);
        }
        return;
    }
    b -= NB_CVT;
    if (b < NB_PACKX) {
        int i = b * 256 + t;            // i < 800768 exactly
        int j = i * 8;                  // output u16 index
        int tile = j >> 11;
        int jj = j & 2047;
        int r = tile * 16 + ((jj >> 3) & 15);
        int k0 = (jj >> 7) * 8;
        uint4 H = {0, 0, 0, 0}, M = {0, 0, 0, 0}, L = {0, 0, 0, 0};
        u16* Hp = (u16*)&H; u16* Mp = (u16*)&M; u16* Lp = (u16*)&L;
        if (r < N_NODES) {
            if (fb) {
                H = *(const uint4*)((const u16*)x + r * D1 + k0);   // exact bf16: mid=lo=0
            } else {
                float4 xa = *(const float4*)((const float*)x + r * D1 + k0);
                float4 xb = *(const float4*)((const float*)x + r * D1 + k0 + 4);
                float vv[8] = {xa.x, xa.y, xa.z, xa.w, xb.x, xb.y, xb.z, xb.w};
#pragma unroll
                for (int e2 = 0; e2 < 8; e2++) split3(vv[e2], Hp[e2], Mp[e2], Lp[e2]);
            }
        }
        *(uint4*)(AH + j) = H;
        *(uint4*)(AM + j) = M;
        *(uint4*)(AL + j) = L;
        return;
    }
    b -= NB_PACKX;
    if (b < 128) {
        int i = b * 256 + t;           // i < 32768
        int k = i >> 8, n = i & 255;
        float v = (n < 128) ? load_f32(Wl1, k * 128 + n, fb)
                            : load_f32(Wr1, k * 128 + (n - 128), fb);
        u16 hi, mid, lo; split3(v, hi, mid, lo);
        int idx = ((k >> 3) * 256 + n) * 8 + (k & 7);
        B1H[idx] = hi; B1M[idx] = mid; B1L[idx] = lo;
        return;
    }
    b -= 128;
    if (b < 64) {
        int i = b * 256 + t;           // i < 16384
        int k = i >> 7, n = i & 127;
        float v = (n < 64) ? load_f32(Wl2, k * 64 + n, fb)
                           : load_f32(Wr2, k * 64 + (n - 64), fb);
        u16 hi, mid, lo; split3(v, hi, mid, lo);
        int idx = ((k >> 3) * 128 + n) * 8 + (k & 7);
        B2H[idx] = hi; B2M[idx] = mid; B2L[idx] = lo;
        return;
    }
    if (t < 128) {
        Wf[W_BL1 + t]   = load_f32(bl1, t, fb);
        Wf[W_BR1 + t]   = load_f32(br1, t, fb);
        Wf[W_ATT1 + t]  = load_f32(att1, t, fb);
        Wf[W_BIAS1 + t] = load_f32(bias1, t, fb);
        if (t < 64) {
            Wf[W_BL2 + t]   = load_f32(bl2, t, fb);
            Wf[W_BR2 + t]   = load_f32(br2, t, fb);
            Wf[W_ATT2 + t]  = load_f32(att2, t, fb);
            Wf[W_BIAS2 + t] = load_f32(bias2, t, fb);
        }
    }
}

// ---- sa: scanA block-sums (0..195) || LDS-privatized degree histogram (196..391) ----
__global__ __launch_bounds__(256) void sa_k(const int* __restrict__ deg, int* __restrict__ part,
                                            int* __restrict__ hist) {
    int b = blockIdx.x, t = threadIdx.x;
    if (b < NB_SCAN) {
        __shared__ int s[256];
        int i = b * 256 + t;
        s[t] = (i < N_NODES) ? deg[i] : 0;
        __syncthreads();
        for (int off = 128; off > 0; off >>= 1) {
            if (t < off) s[t] += s[t + off];
            __syncthreads();
        }
        if (t == 0) part[b] = s[0];
        return;
    }
    __shared__ int lh[256];
    lh[t] = 0;
    __syncthreads();
    int i = (b - NB_SCAN) * 256 + t;
    if (i < N_NODES) atomicAdd(&lh[min(deg[i], 255)], 1);   // LDS atomic: block-local
    __syncthreads();
    if (lh[t]) atomicAdd(&hist[t], lh[t]);                  // one global atomic per (block,bucket)
}

// ---- sb: block0 = scan part[196]; block1 = bucket offsets from hist ----
__global__ __launch_bounds__(256) void sb_k(int* __restrict__ part, const int* __restrict__ hist,
                                            int* __restrict__ bcur) {
    __shared__ int s[256];
    int t = threadIdx.x;
    if (blockIdx.x == 0) {
        s[t] = (t < NB_SCAN) ? part[t] : 0;
        __syncthreads();
        for (int off = 1; off < 256; off <<= 1) {
            int v = (t >= off) ? s[t - off] : 0;
            __syncthreads();
            s[t] += v;
            __syncthreads();
        }
        if (t < NB_SCAN) part[t] = (t == 0) ? 0 : s[t - 1];
        return;
    }
    int h = hist[t];
    s[t] = h;
    __syncthreads();
    for (int off = 1; off < 256; off <<= 1) {
        int v = (t >= off) ? s[t - off] : 0;
        __syncthreads();
        s[t] += v;
        __syncthreads();
    }
    bcur[t] = s[t] - h;   // exclusive
}

// ---- sc: rowptr (0..195) || block-aggregated perm scatter (196..391) ----
__global__ __launch_bounds__(256) void sc_k(const int* __restrict__ deg, const int* __restrict__ part,
                                            int* __restrict__ rowptr,
                                            int* __restrict__ bcur, int* __restrict__ perm) {
    int b = blockIdx.x, t = threadIdx.x;
    if (b < NB_SCAN) {
        __shared__ int s[256];
        int i = b * 256 + t;
        int v = (i < N_NODES) ? deg[i] : 0;
        s[t] = v;
        __syncthreads();
        for (int off = 1; off < 256; off <<= 1) {
            int u = (t >= off) ? s[t - off] : 0;
            __syncthreads();
            s[t] += u;
            __syncthreads();
        }
        int excl = part[b] + s[t] - v;
        if (i < N_NODES) rowptr[i] = excl;
        if (i == N_NODES - 1) rowptr[N_NODES] = excl + v;
        return;
    }
    __shared__ int lh[256];
    __shared__ int lbase[256];
    lh[t] = 0;
    __syncthreads();
    int i = (b - NB_SCAN) * 256 + t;
    int bk = -1, myrank = 0;
    if (i < N_NODES) {
        bk = min(deg[i], 255);
        myrank = atomicAdd(&lh[bk], 1);     // LDS atomic
    }
    __syncthreads();
    if (lh[t]) lbase[t] = atomicAdd(&bcur[t], lh[t]);   // 1 global atomic per bucket
    __syncthreads();
    if (bk >= 0) perm[lbase[bk] + myrank] = i;
}

// 6-term split-precision MFMA accumulate: acc += A*B with ~2^-24 relative error
#define MFMA6(acc, ah, am, al, bh, bm, bl)                                    \
    acc = __builtin_amdgcn_mfma_f32_16x16x32_bf16(ah, bl, acc, 0, 0, 0);      \
    acc = __builtin_amdgcn_mfma_f32_16x16x32_bf16(am, bm, acc, 0, 0, 0);      \
    acc = __builtin_amdgcn_mfma_f32_16x16x32_bf16(al, bh, acc, 0, 0, 0);      \
    acc = __builtin_amdgcn_mfma_f32_16x16x32_bf16(ah, bm, acc, 0, 0, 0);      \
    acc = __builtin_amdgcn_mfma_f32_16x16x32_bf16(am, bh, acc, 0, 0, 0);      \
    acc = __builtin_amdgcn_mfma_f32_16x16x32_bf16(ah, bh, acc, 0, 0, 0);

// ---- sg: gemm1 (blocks [0,NB_G1)) || atomic-free csr scatter ----
__global__ __launch_bounds__(256) void sg_k(const u16* __restrict__ AH, const u16* __restrict__ AM,
                                            const u16* __restrict__ AL,
                                            const u16* __restrict__ BH, const u16* __restrict__ BM,
                                            const u16* __restrict__ BL,
                                            const float* __restrict__ Wf,
                                            float* __restrict__ xl, float* __restrict__ xr,
                                            const u16* __restrict__ srcA, const u16* __restrict__ dstA,
                                            const u16* __restrict__ rank, const int* __restrict__ rowptr,
                                            u16* __restrict__ csr) {
    int b = blockIdx.x;
    if (b < NB_G1) {
        int w = threadIdx.x >> 6, l = threadIdx.x & 63;
        int tile = (b >> 2) * 4 + w;
        int cb = (b & 3) << 6;                 // col base (0,64,128,192)
        int lr = l & 15, lg = l >> 4;
        f4v acc[4];
#pragma unroll
        for (int nt = 0; nt < 4; nt++) acc[nt] = (f4v)(0.f);
        int aoff = tile * 2048 + lg * 128 + lr * 8;
#pragma unroll
        for (int ks = 0; ks < 4; ks++) {
            bf8v ah = *(const bf8v*)(AH + aoff + ks * 512);
            bf8v am = *(const bf8v*)(AM + aoff + ks * 512);
            bf8v al = *(const bf8v*)(AL + aoff + ks * 512);
            int boff = ((ks * 4 + lg) * 256 + cb + lr) * 8;
#pragma unroll
            for (int nt = 0; nt < 4; nt++) {
                bf8v bh = *(const bf8v*)(BH + boff + nt * 128);
                bf8v bm = *(const bf8v*)(BM + boff + nt * 128);
                bf8v bl = *(const bf8v*)(BL + boff + nt * 128);
                MFMA6(acc[nt], ah, am, al, bh, bm, bl)
            }
        }
        int r0 = tile * 16 + lg * 4;
        if (r0 >= N_NODES) return;
#pragma unroll
        for (int nt = 0; nt < 4; nt++) {
            int col = cb + nt * 16 + lr;
            float bias = (col < D1) ? Wf[W_BL1 + col] : Wf[W_BR1 + col - D1];
            float* dst = (col < D1) ? (xl + col) : (xr + col - D1);
#pragma unroll
            for (int j = 0; j < 4; j++) {
                int row = r0 + j;
                dst[(size_t)row * D1] = acc[nt][j] + bias;
            }
        }
        return;
    }
    int e = (b - NB_G1) * 256 + threadIdx.x;
    if (e < ET) {
        int d = dstA[e];
        csr[rowptr[d] + rank[e]] = srcA[e];    // unique slot, no atomic
    }
}

// MFMA GEMM 2: A read from f32 h rows, in-register split3. Grid (782, 2) x 256 thr.
union bfu { bf8v v; u16 s[8]; };
__global__ __launch_bounds__(256) void gemm2_mfma(const float* __restrict__ hA,
                                                  const u16* __restrict__ BH, const u16* __restrict__ BM,
                                                  const u16* __restrict__ BL,
                                                  const float* __restrict__ Wf,
                                                  float* __restrict__ xl2, float* __restrict__ xr2) {
    int w = threadIdx.x >> 6, l = threadIdx.x & 63;
    int tile = blockIdx.x * 4 + w;
    int cb = blockIdx.y << 6;                 // col base (0,64)
    int lr = l & 15, lg = l >> 4;
    int r = tile * 16 + lr;
    int rc = min(r, N_NODES - 1);             // pad rows read row 49999; stores guarded off
    f4v acc[4];
#pragma unroll
    for (int nt = 0; nt < 4; nt++) acc[nt] = (f4v)(0.f);
#pragma unroll
    for (int ks = 0; ks < 4; ks++) {
        const float* hp = hA + (size_t)rc * D1 + ks * 32 + lg * 8;
        float4 p0 = *(const float4*)hp;
        float4 p1 = *(const float4*)(hp + 4);
        float vv[8] = {p0.x, p0.y, p0.z, p0.w, p1.x, p1.y, p1.z, p1.w};
        bfu ah, am, al;
#pragma unroll
        for (int j = 0; j < 8; j++) split3(vv[j], ah.s[j], am.s[j], al.s[j]);
        int boff = ((ks * 4 + lg) * 128 + cb + lr) * 8;
#pragma unroll
        for (int nt = 0; nt < 4; nt++) {
            bf8v bh = *(const bf8v*)(BH + boff + nt * 128);
            bf8v bm = *(const bf8v*)(BM + boff + nt * 128);
            bf8v bl = *(const bf8v*)(BL + boff + nt * 128);
            MFMA6(acc[nt], ah.v, am.v, al.v, bh, bm, bl)
        }
    }
    int r0 = tile * 16 + lg * 4;
    if (r0 >= N_NODES) return;
#pragma unroll
    for (int nt = 0; nt < 4; nt++) {
        int col = cb + nt * 16 + lr;
        float bias = (col < D2) ? Wf[W_BL2 + col] : Wf[W_BR2 + col - D2];
        float* dst = (col < D2) ? (xl2 + col) : (xr2 + col - D2);
#pragma unroll
        for (int j = 0; j < 4; j++) {
            int row = r0 + j;
            dst[(size_t)row * D2] = acc[nt][j] + bias;
        }
    }
}

// layer-1 aggregation: degree-sorted nodes (perm), 32 lanes/node, no-max softmax (exp2,
// att pre-scaled by log2e, med3 clamp), 2-deep gather prefetch, + bias1 + ELU -> f32 h rows.
#define L1STEP(a)                                                              \
    {                                                                          \
        float m0 = a.x + xr4.x; m0 = fmaxf(m0, NEG * m0);                      \
        float m1 = a.y + xr4.y; m1 = fmaxf(m1, NEG * m1);                      \
        float m2 = a.z + xr4.z; m2 = fmaxf(m2, NEG * m2);                      \
        float m3 = a.w + xr4.w; m3 = fmaxf(m3, NEG * m3);                      \
        float p = m0 * at4.x + m1 * at4.y + m2 * at4.z + m3 * at4.w;           \
        p += __shfl_xor(p, 1);                                                 \
        p += __shfl_xor(p, 2);                                                 \
        p = __builtin_amdgcn_fmed3f(p, -86.f, 86.f);                           \
        float wgt = exp2f(p);                                                  \
        l += wgt;                                                              \
        acc.x = fmaf(wgt, a.x, acc.x);                                         \
        acc.y = fmaf(wgt, a.y, acc.y);                                         \
        acc.z = fmaf(wgt, a.z, acc.z);                                         \
        acc.w = fmaf(wgt, a.w, acc.w);                                         \
    }

__global__ __launch_bounds__(256) void l1_agg(const int* __restrict__ rowptr, const u16* __restrict__ csr,
                                              const int* __restrict__ perm,
                                              const float* __restrict__ xl, const float* __restrict__ xr,
                                              const float* __restrict__ Wf, float* __restrict__ hbuf) {
    int n = perm[(blockIdx.x * 256 + threadIdx.x) >> 5];
    int q = threadIdx.x & 31;                        // channels 4q..4q+3
    const float4* xl4 = (const float4*)xl;
    float4 xr4 = ((const float4*)(xr + (size_t)n * D1))[q];
    float4 at4 = ((const float4*)(Wf + W_ATT1))[q];
    at4.x *= LOG2E; at4.y *= LOG2E; at4.z *= LOG2E; at4.w *= LOG2E;
    int i0 = rowptr[n], i1 = rowptr[n + 1];
    float l = 0.f;
    float4 acc = {0.f, 0.f, 0.f, 0.f};
    float4 a0 = xl4[(size_t)csr[i0] * 32 + q];       // deg >= 1 (self-loop)
    if (i0 + 1 < i1) {
        float4 a1 = xl4[(size_t)csr[i0 + 1] * 32 + q];
        for (int i = i0 + 2; i < i1; i++) {
            float4 a2 = xl4[(size_t)csr[i] * 32 + q];  // 2-deep prefetch
            L1STEP(a0)
            a0 = a1; a1 = a2;
        }
        L1STEP(a0)
        a0 = a1;
    }
    L1STEP(a0)
    float rinv = 1.f / l;
    float4 bi4 = ((const float4*)(Wf + W_BIAS1))[q];
    float v0 = acc.x * rinv + bi4.x; v0 = v0 > 0.f ? v0 : expm1f(v0);
    float v1 = acc.y * rinv + bi4.y; v1 = v1 > 0.f ? v1 : expm1f(v1);
    float v2 = acc.z * rinv + bi4.z; v2 = v2 > 0.f ? v2 : expm1f(v2);
    float v3 = acc.w * rinv + bi4.w; v3 = v3 > 0.f ? v3 : expm1f(v3);
    float4 hv = {v0, v1, v2, v3};
    ((float4*)(hbuf + (size_t)n * D1))[q] = hv;      // contiguous 512B/node, perm-safe
}

// layer-2 aggregation: degree-sorted nodes (perm), 16 lanes/node, no-max softmax (exp2),
// 2-deep prefetch, + bias2 + log_softmax + argmax. Grid 3125 x 256.
#define L2STEP(a)                                                              \
    {                                                                          \
        float m0 = a.x + xr4.x; m0 = fmaxf(m0, NEG * m0);                      \
        float m1 = a.y + xr4.y; m1 = fmaxf(m1, NEG * m1);                      \
        float m2 = a.z + xr4.z; m2 = fmaxf(m2, NEG * m2);                      \
        float m3 = a.w + xr4.w; m3 = fmaxf(m3, NEG * m3);                      \
        float p = m0 * at4.x + m1 * at4.y + m2 * at4.z + m3 * at4.w;           \
        p += __shfl_xor(p, 1);                                                 \
        p += __shfl_xor(p, 2);                                                 \
        p += __shfl_xor(p, 4);                                                 \
        p += __shfl_xor(p, 8);                                                 \
        p = __builtin_amdgcn_fmed3f(p, -115.f, 115.f);                         \
        float wgt = exp2f(p);                                                  \
        l += wgt;                                                              \
        acc.x = fmaf(wgt, a.x, acc.x);                                         \
        acc.y = fmaf(wgt, a.y, acc.y);                                         \
        acc.z = fmaf(wgt, a.z, acc.z);                                         \
        acc.w = fmaf(wgt, a.w, acc.w);                                         \
    }

__global__ __launch_bounds__(256) void l2_agg(const int* __restrict__ rowptr, const u16* __restrict__ csr,
                                              const int* __restrict__ perm,
                                              const float* __restrict__ xl, const float* __restrict__ xr,
                                              const float* __restrict__ Wf, float* __restrict__ out) {
    int n = perm[(blockIdx.x * 256 + threadIdx.x) >> 4];
    int q = threadIdx.x & 15;                        // channels 4q..4q+3
    const float4* xl4 = (const float4*)xl;
    float4 xr4 = ((const float4*)(xr + (size_t)n * D2))[q];
    float4 at4 = ((const float4*)(Wf + W_ATT2))[q];
    at4.x *= LOG2E; at4.y *= LOG2E; at4.z *= LOG2E; at4.w *= LOG2E;
    int i0 = rowptr[n], i1 = rowptr[n + 1];
    float l = 0.f;
    float4 acc = {0.f, 0.f, 0.f, 0.f};
    float4 a0 = xl4[(size_t)csr[i0] * 16 + q];
    if (i0 + 1 < i1) {
        float4 a1 = xl4[(size_t)csr[i0 + 1] * 16 + q];
        for (int i = i0 + 2; i < i1; i++) {
            float4 a2 = xl4[(size_t)csr[i] * 16 + q];
            L2STEP(a0)
            a0 = a1; a1 = a2;
        }
        L2STEP(a0)
        a0 = a1;
    }
    L2STEP(a0)
    float rinv = 1.f / (l + EPSF);
    float4 bi4 = ((const float4*)(Wf + W_BIAS2))[q];
    float v0 = acc.x * rinv + bi4.x;
    float v1 = acc.y * rinv + bi4.y;
    float v2 = acc.z * rinv + bi4.z;
    float v3 = acc.w * rinv + bi4.w;
    float4 hv = {v0, v1, v2, v3};
    ((float4*)(out + (size_t)n * D2))[q] = hv;
    // log-softmax over 64 classes = 16 lanes x 4
    float mx = fmaxf(fmaxf(v0, v1), fmaxf(v2, v3));
#pragma unroll
    for (int off = 1; off < 16; off <<= 1) mx = fmaxf(mx, __shfl_xor(mx, off));
    float sum = expf(v0 - mx) + expf(v1 - mx) + expf(v2 - mx) + expf(v3 - mx);
#pragma unroll
    for (int off = 1; off < 16; off <<= 1) sum += __shfl_xor(sum, off);
    float lse = mx + logf(sum);
    float4 ls = {v0 - lse, v1 - lse, v2 - lse, v3 - lse};
    ((float4*)(out + (size_t)N_NODES * D2 + (size_t)n * D2))[q] = ls;
    // argmax, first occurrence on ties (channels 4q+j are lane-contiguous)
    float bv = v0; int bi = 4 * q;
    if (v1 > bv) { bv = v1; bi = 4 * q + 1; }
    if (v2 > bv) { bv = v2; bi = 4 * q + 2; }
    if (v3 > bv) { bv = v3; bi = 4 * q + 3; }
#pragma unroll
    for (int off = 1; off < 16; off <<= 1) {
        float ov = __shfl_xor(bv, off);
        int   oi = __shfl_xor(bi, off);
        if (ov > bv || (ov == bv && oi < bi)) { bv = ov; bi = oi; }
    }
    if (q == 0) out[(size_t)2 * N_NODES * D2 + n] = (float)bi;
}

extern "C" void kernel_launch(void* const* d_in, const int* in_sizes, int n_in,
                              void* d_out, int out_size, void* d_ws, size_t ws_size,
                              hipStream_t stream) {
    const void* x  = d_in[0];
    const int*  ei = (const int*)d_in[1];

    float* ws = (float*)d_ws;
    float* xl1    = ws + O_XL1;
    float* xr1    = ws + O_XR1;
    u16*   AH     = (u16*)(ws + O_AH);
    u16*   AM     = (u16*)(ws + O_AM);
    u16*   AL     = (u16*)(ws + O_AL);
    float* hbuf   = ws + O_AH;           // f32 h reuses A-plane region after gemm1
    u16*   B1H    = (u16*)(ws + O_B1H);
    u16*   B1M    = (u16*)(ws + O_B1M);
    u16*   B1L    = (u16*)(ws + O_B1L);
    u16*   B2H    = (u16*)(ws + O_B2H);
    u16*   B2M    = (u16*)(ws + O_B2M);
    u16*   B2L    = (u16*)(ws + O_B2L);
    float* Wf     = ws + O_WF;
    u16*   srcA   = (u16*)(ws + O_SRC);
    u16*   dstA   = (u16*)(ws + O_DST);
    int*   deg    = (int*)(ws + O_DEG);
    int*   rowptr = (int*)(ws + O_ROWPTR);
    u16*   rank   = (u16*)(ws + O_RANK);
    u16*   csr    = (u16*)(ws + O_CSR);
    int*   flags  = (int*)(ws + O_FLAGS);
    int*   part   = (int*)(ws + O_PART);
    int*   hist   = (int*)(ws + O_HIST);
    int*   bcur   = (int*)(ws + O_BCUR);
    int*   perm   = (int*)(ws + O_PERM);

    float* xl2 = xl1;
    float* xr2 = xl1 + 3200000;

    hipMemsetAsync(deg, 0, N_NODES * sizeof(int), stream);
    hipMemsetAsync(hist, 0, 256 * sizeof(int), stream);
    detect_k<<<1, 256, 0, stream>>>((const uint4*)x, ei, flags);
    prep_k<<<NB_PREP, 256, 0, stream>>>(ei, srcA, dstA, rank, deg,
                                        x, AH, AM, AL,
                                        d_in[2], d_in[4], B1H, B1M, B1L,
                                        d_in[8], d_in[10], B2H, B2M, B2L,
                                        d_in[3], d_in[5], d_in[6], d_in[7],
                                        d_in[9], d_in[11], d_in[12], d_in[13],
                                        Wf, flags);
    sa_k<<<2 * NB_SCAN, 256, 0, stream>>>(deg, part, hist);
    sb_k<<<2, 256, 0, stream>>>(part, hist, bcur);
    sc_k<<<2 * NB_SCAN, 256, 0, stream>>>(deg, part, rowptr, bcur, perm);
    sg_k<<<NB_SG, 256, 0, stream>>>(AH, AM, AL, B1H, B1M, B1L, Wf, xl1, xr1,
                                    srcA, dstA, rank, rowptr, csr);

    l1_agg<<<6250, 256, 0, stream>>>(rowptr, csr, perm, xl1, xr1, Wf, hbuf);
    gemm2_mfma<<<dim3(NTILES_PAD / 4, 2), 256, 0, stream>>>(hbuf, B2H, B2M, B2L, Wf, xl2, xr2);
    l2_agg<<<3125, 256, 0, stream>>>(rowptr, csr, perm, xl2, xr2, Wf, (float*)d_out);
}